// Round 3
// baseline (1104.437 us; speedup 1.0000x reference)
//
#include <hip/hip_runtime.h>
#include <hip/hip_bf16.h>

// ScaledDotProductAttention: B=2,H=16,S=2048,D=64, T=8, outputs (O, attn) fp32.
// R4 (re-run; prior attempt hit infra failure): (a) deferred attn writeback — tile
// kt's P is stored at the TOP of iteration kt+1 so the pre-barrier vmcnt(0) drain
// overlaps a full tile of compute; (b) nontemporal attn/O stores (keep K/V in L2);
// (c) single fused prep kernel (mask pack + K bf16 swizzle + V^T bf16 tile swizzle).

using short4v = __attribute__((ext_vector_type(4))) short;
using short8v = __attribute__((ext_vector_type(8))) short;
using float4v = __attribute__((ext_vector_type(4))) float;

#define S_LEN 2048
#define D_DIM 64
#define QT 64                 // q rows per block
#define KTILE 64              // k cols per iteration
#define NIT (S_LEN / KTILE)   // 32
#define NW (S_LEN / 64)       // 32 packed 64-bit words per mask row
#define LDK 72                // padded LDS row stride (shorts) for lds_p / fallback
#define ATTN_OFF (2 * 16 * 2048 * 64)
#define TILE_SH (KTILE * D_DIM)  // 4096 shorts = 8 KiB per tile

typedef __attribute__((address_space(1))) const unsigned int gu32;
typedef __attribute__((address_space(3))) unsigned int lu32;

__device__ __forceinline__ short f2bf(float x) {
  __hip_bfloat16 h = __float2bfloat16(x);
  return __builtin_bit_cast(short, h);
}
__device__ __forceinline__ float bf2f(short s) {
  return __builtin_bit_cast(float, ((unsigned)(unsigned short)s) << 16);
}

// ---------------- fused prep: K swizzle + V^T tile swizzle + mask pack ----------------
// blocks [0,2048): K fp32 -> bf16 XOR-swizzled rows.
//   stored[kr][slot] (16B granules) = K[kr][(slot^(kr&7))*8 ..+8]
// blocks [2048,3072): V fp32 -> bf16 transposed tiles, swizzled.
//   vts tile (bh,kt): stored[d][slot] = V[kt*64 + (slot^(d&7))*8 ..+8][d]
// blocks [3072,3328): mask int32 -> 64-col bitmask words.
__global__ __launch_bounds__(256) void prep_kernel(
    const float* __restrict__ k, const float* __restrict__ v,
    const int* __restrict__ mask, short* __restrict__ kbs,
    short* __restrict__ vts, unsigned long long* __restrict__ pm, int nwords) {
  __shared__ short lds_t[64 * 72];
  const int tid = threadIdx.x;
  const int bid = blockIdx.x;
  if (bid < 2048) {
    int g = bid * 256 + tid;  // granule id, 0..524287
    int kr = g >> 3;          // global row (bh*2048 + s)
    int slot = g & 7;
    const float* src = k + (size_t)kr * D_DIM + ((slot ^ (kr & 7)) << 3);
    float4v a = *(const float4v*)src;
    float4v b = *(const float4v*)(src + 4);
    short8v t;
    t[0] = f2bf(a[0]); t[1] = f2bf(a[1]); t[2] = f2bf(a[2]); t[3] = f2bf(a[3]);
    t[4] = f2bf(b[0]); t[5] = f2bf(b[1]); t[6] = f2bf(b[2]); t[7] = f2bf(b[3]);
    *(short8v*)(kbs + (size_t)g * 8) = t;
  } else if (bid < 3072) {
    const int vb = bid - 2048;
    const int bh = vb >> 5;
    const int kt = vb & 31;
    const float* vp = v + ((size_t)bh * S_LEN + kt * KTILE) * D_DIM;
#pragma unroll
    for (int i = 0; i < 4; ++i) {
      int idx = tid + i * 256;  // 0..1023, 4 floats each
      int s = idx >> 4;         // seq within tile
      int d0 = (idx & 15) * 4;
      float4v x = *(const float4v*)(vp + (size_t)s * D_DIM + d0);
#pragma unroll
      for (int j = 0; j < 4; ++j) lds_t[(d0 + j) * 72 + s] = f2bf(x[j]);
    }
    __syncthreads();
    short* dst = vts + (size_t)vb * TILE_SH;
#pragma unroll
    for (int i = 0; i < 2; ++i) {
      int g = tid + i * 256;  // 0..511 granules
      int d = g >> 3;
      int slot = g & 7;
      int lsrc = slot ^ (d & 7);
      short8v t = *(const short8v*)(lds_t + d * 72 + lsrc * 8);
      *(short8v*)(dst + g * 8) = t;
    }
  } else {
    const int lane = tid & 63;
    int gw = ((bid - 3072) * 256 + tid) >> 6;
    const int stride = (256 * 256) >> 6;  // 1024
    for (int w = gw; w < nwords; w += stride) {
      int m = mask[(size_t)w * 64 + lane];
      unsigned long long bits = __ballot(m != 0);
      if (lane == 0) pm[w] = bits;
    }
  }
}

// standalone mask pack (middle fallback path)
__global__ __launch_bounds__(256) void pack_mask_kernel(
    const int* __restrict__ mask, unsigned long long* __restrict__ pm, int nwords) {
  const int lane = threadIdx.x & 63;
  int gw = (blockIdx.x * blockDim.x + threadIdx.x) >> 6;
  const int stride = (gridDim.x * blockDim.x) >> 6;
  for (int w = gw; w < nwords; w += stride) {
    int m = mask[(size_t)w * 64 + lane];
    unsigned long long bits = __ballot(m != 0);
    if (lane == 0) pm[w] = bits;
  }
}

// ---------------- async stage: one wave moves 2 KiB of an 8 KiB tile ----------------
__device__ __forceinline__ void stage_wave(const short* __restrict__ g, short* l,
                                           int wave, int lane) {
  const short* s0 = g + wave * 1024 + lane * 8;  // per-lane 16B source
  short* d0 = l + wave * 1024;                   // wave-uniform LDS base
  __builtin_amdgcn_global_load_lds((gu32*)s0, (lu32*)d0, 16, 0, 0);
  __builtin_amdgcn_global_load_lds((gu32*)(s0 + 512), (lu32*)(d0 + 512), 16, 0, 0);
}

// ---------------- main fused kernel ----------------
__global__ __launch_bounds__(256, 3) void sdpa_fused(
    const float* __restrict__ q, const short* __restrict__ kbs,
    const short* __restrict__ vts, const unsigned long long* __restrict__ pm,
    float* __restrict__ out) {
  __shared__ __align__(16) short lds_k[2][TILE_SH];   // K tiles, swizzled bf16
  __shared__ __align__(16) short lds_vt[2][TILE_SH];  // V^T tiles, swizzled bf16
  __shared__ short lds_p[QT * LDK];                   // P tile bf16 (per-wave rows)

  const int tid  = threadIdx.x;
  const int wave = tid >> 6;
  const int lane = tid & 63;
  const int quad = lane >> 4;
  const int l16  = lane & 15;

  // XCD-aware swizzle: 1024 wgs, 8 XCDs -> contiguous 128-block chunk per XCD
  const int blk = (blockIdx.x & 7) * 128 + (blockIdx.x >> 3);
  const int qt  = blk & (NIT - 1);
  const int bh  = blk >> 5;
  const int b   = bh >> 4;

  const float* qp = q + (size_t)bh * S_LEN * D_DIM;
  const short* kb_g = kbs + (size_t)bh * S_LEN * D_DIM;
  const short* vt_g = vts + (size_t)bh * (NIT * TILE_SH);
  float* outO = out + (size_t)bh * S_LEN * D_DIM;
  float* outA = out + (size_t)ATTN_OFF + (size_t)bh * S_LEN * S_LEN;

  const int qbase = qt * QT;
  const int qrowC = qbase + wave * 16 + quad * 4;  // C/D: row = quad*4 + reg

  // ---- Q fragments; scale log2(e)/8 folded in ----
  const float QSCALE = 0.18033688011112042f;
  short8v qa[2];
  {
    const int qrow = qbase + wave * 16 + l16;  // A-operand: m = lane&15
    const float* src = qp + (size_t)qrow * D_DIM + quad * 8;
#pragma unroll
    for (int c = 0; c < 2; ++c) {
      float4v x0 = *(const float4v*)(src + c * 32);
      float4v x1 = *(const float4v*)(src + c * 32 + 4);
      short8v t;
      t[0] = f2bf(x0[0] * QSCALE); t[1] = f2bf(x0[1] * QSCALE);
      t[2] = f2bf(x0[2] * QSCALE); t[3] = f2bf(x0[3] * QSCALE);
      t[4] = f2bf(x1[0] * QSCALE); t[5] = f2bf(x1[1] * QSCALE);
      t[6] = f2bf(x1[2] * QSCALE); t[7] = f2bf(x1[3] * QSCALE);
      qa[c] = t;
    }
  }

  const unsigned long long* pmrow = pm + ((size_t)b * S_LEN + qrowC) * NW;

  // ================= pass 1: row sums of exp =================
  float lsum[4] = {0.f, 0.f, 0.f, 0.f};
  unsigned long long mrow_c[4];
  unsigned long long mrow_n[4] = {0ull, 0ull, 0ull, 0ull};
#pragma unroll
  for (int r = 0; r < 4; ++r) mrow_c[r] = pmrow[(size_t)r * NW];
  stage_wave(kb_g, lds_k[0], wave, lane);
  __syncthreads();

#pragma unroll 1
  for (int kt = 0; kt < NIT; ++kt) {
    if (kt + 1 < NIT) {
#pragma unroll
      for (int r = 0; r < 4; ++r) mrow_n[r] = pmrow[(size_t)r * NW + kt + 1];
      stage_wave(kb_g + (kt + 1) * TILE_SH, lds_k[(kt + 1) & 1], wave, lane);
    }
    const short* kbuf = lds_k[kt & 1];
#pragma unroll
    for (int t = 0; t < 4; ++t) {
      float4v acc = {0.f, 0.f, 0.f, 0.f};
      const int row = t * 16 + l16;
      const int sw = (row & 7) << 3;  // XOR swizzle, short units (16B granules)
#pragma unroll
      for (int c = 0; c < 2; ++c) {
        short8v bf = *(const short8v*)(kbuf + row * 64 + (((c * 32) + quad * 8) ^ sw));
        acc = __builtin_amdgcn_mfma_f32_16x16x32_bf16(qa[c], bf, acc, 0, 0, 0);
      }
#pragma unroll
      for (int r = 0; r < 4; ++r) {
        bool mv = ((mrow_c[r] >> (t * 16 + l16)) & 1ull) != 0;
        float p = mv ? exp2f(acc[r]) : 0.f;
        lsum[r] += p;
      }
    }
#pragma unroll
    for (int r = 0; r < 4; ++r) mrow_c[r] = mrow_n[r];
    __syncthreads();  // implicit vmcnt(0): tile kt+1 landed; buffers safe
  }

  float invl[4];
#pragma unroll
  for (int r = 0; r < 4; ++r) {
    float s = lsum[r];
    s += __shfl_xor(s, 1);
    s += __shfl_xor(s, 2);
    s += __shfl_xor(s, 4);
    s += __shfl_xor(s, 8);
    invl[r] = 1.0f / s;
  }

  // ================= pass 2: attn write + PV =================
  float4v oacc[4];
#pragma unroll
  for (int dt = 0; dt < 4; ++dt) oacc[dt] = (float4v){0.f, 0.f, 0.f, 0.f};

#pragma unroll
  for (int r = 0; r < 4; ++r) mrow_c[r] = pmrow[(size_t)r * NW];
  stage_wave(kb_g, lds_k[0], wave, lane);
  stage_wave(vt_g, lds_vt[0], wave, lane);
  __syncthreads();

  // deferred attn writeback state (tile kt-1's P, read back into regs in iter kt-1)
  const int row16 = lane >> 2;
  const int cg = (lane & 3) * 16;
  float* arow_base = outA + (size_t)(qbase + wave * 16 + row16) * S_LEN + cg;
  short8v pp0, pp1;

#pragma unroll 1
  for (int kt = 0; kt < NIT; ++kt) {
    // (1) deferred attn store of tile kt-1: issued at top so it drains during
    // this iteration's compute instead of stalling the pre-barrier vmcnt(0).
    if (kt > 0) {
      float* arow = arow_base + (kt - 1) * KTILE;
      float4v f0 = {bf2f(pp0[0]), bf2f(pp0[1]), bf2f(pp0[2]), bf2f(pp0[3])};
      float4v f1 = {bf2f(pp0[4]), bf2f(pp0[5]), bf2f(pp0[6]), bf2f(pp0[7])};
      float4v f2 = {bf2f(pp1[0]), bf2f(pp1[1]), bf2f(pp1[2]), bf2f(pp1[3])};
      float4v f3 = {bf2f(pp1[4]), bf2f(pp1[5]), bf2f(pp1[6]), bf2f(pp1[7])};
      __builtin_nontemporal_store(f0, (float4v*)(arow));
      __builtin_nontemporal_store(f1, (float4v*)(arow + 4));
      __builtin_nontemporal_store(f2, (float4v*)(arow + 8));
      __builtin_nontemporal_store(f3, (float4v*)(arow + 12));
    }
    // (2) next-tile mask + K/V prefetch
    if (kt + 1 < NIT) {
#pragma unroll
      for (int r = 0; r < 4; ++r) mrow_n[r] = pmrow[(size_t)r * NW + kt + 1];
      stage_wave(kb_g + (kt + 1) * TILE_SH, lds_k[(kt + 1) & 1], wave, lane);
      stage_wave(vt_g + (kt + 1) * TILE_SH, lds_vt[(kt + 1) & 1], wave, lane);
    }
    const short* kbuf = lds_k[kt & 1];
    const short* vbuf = lds_vt[kt & 1];

    // (3) QK^T + P staging
#pragma unroll
    for (int t = 0; t < 4; ++t) {
      float4v acc = {0.f, 0.f, 0.f, 0.f};
      const int row = t * 16 + l16;
      const int sw = (row & 7) << 3;
#pragma unroll
      for (int c = 0; c < 2; ++c) {
        short8v bf = *(const short8v*)(kbuf + row * 64 + (((c * 32) + quad * 8) ^ sw));
        acc = __builtin_amdgcn_mfma_f32_16x16x32_bf16(qa[c], bf, acc, 0, 0, 0);
      }
      short* prow = lds_p + (wave * 16 + quad * 4) * LDK + t * 16 + l16;
#pragma unroll
      for (int r = 0; r < 4; ++r) {
        bool mv = ((mrow_c[r] >> (t * 16 + l16)) & 1ull) != 0;
        float p = mv ? exp2f(acc[r]) * invl[r] : 0.f;
        prow[r * LDK] = f2bf(p);  // stage P (C/D -> A layout via LDS)
      }
    }

    // (4) same-wave P readback into carry registers (DS in-order per wave)
    {
      const short* src = lds_p + (wave * 16 + row16) * LDK + cg;
      pp0 = *(const short8v*)src;
      pp1 = *(const short8v*)(src + 8);
    }

    // (5) PV
#pragma unroll
    for (int c = 0; c < 2; ++c) {
      short8v pa = *(const short8v*)(lds_p + (wave * 16 + l16) * LDK + c * 32 + quad * 8);
#pragma unroll
      for (int dt = 0; dt < 4; ++dt) {
        const int row = dt * 16 + l16;
        const int sw = (row & 7) << 3;
        short8v vb = *(const short8v*)(vbuf + row * 64 + (((c * 32) + quad * 8) ^ sw));
        oacc[dt] = __builtin_amdgcn_mfma_f32_16x16x32_bf16(pa, vb, oacc[dt], 0, 0, 0);
      }
    }
#pragma unroll
    for (int r = 0; r < 4; ++r) mrow_c[r] = mrow_n[r];
    __syncthreads();
  }

  // final tile's deferred attn store
  {
    float* arow = arow_base + (NIT - 1) * KTILE;
    float4v f0 = {bf2f(pp0[0]), bf2f(pp0[1]), bf2f(pp0[2]), bf2f(pp0[3])};
    float4v f1 = {bf2f(pp0[4]), bf2f(pp0[5]), bf2f(pp0[6]), bf2f(pp0[7])};
    float4v f2 = {bf2f(pp1[0]), bf2f(pp1[1]), bf2f(pp1[2]), bf2f(pp1[3])};
    float4v f3 = {bf2f(pp1[4]), bf2f(pp1[5]), bf2f(pp1[6]), bf2f(pp1[7])};
    __builtin_nontemporal_store(f0, (float4v*)(arow));
    __builtin_nontemporal_store(f1, (float4v*)(arow + 4));
    __builtin_nontemporal_store(f2, (float4v*)(arow + 8));
    __builtin_nontemporal_store(f3, (float4v*)(arow + 12));
  }

  {
    float* orow = outO + (size_t)qrowC * D_DIM + l16;
#pragma unroll
    for (int dt = 0; dt < 4; ++dt) {
#pragma unroll
      for (int r = 0; r < 4; ++r) {
        __builtin_nontemporal_store(oacc[dt][r], orow + (size_t)r * D_DIM + dt * 16);
      }
    }
  }
}

// ================= fallback (R2 kernel, small workspace) =================
template <bool PACKED>
__global__ __launch_bounds__(256, 4) void sdpa_kernel(
    const float* __restrict__ q, const float* __restrict__ k,
    const float* __restrict__ v, const int* __restrict__ mask,
    const unsigned long long* __restrict__ pm, float* __restrict__ out) {
  __shared__ short lds_k[KTILE * LDK];
  __shared__ short lds_vt[D_DIM * LDK];
  __shared__ short lds_p[QT * LDK];

  const int tid  = threadIdx.x;
  const int wave = tid >> 6;
  const int lane = tid & 63;
  const int quad = lane >> 4;
  const int l16  = lane & 15;

  const int blk = blockIdx.x;
  const int qt  = blk & (NIT - 1);
  const int bh  = blk >> 5;
  const int b   = bh >> 4;

  const float* qp = q + (size_t)bh * S_LEN * D_DIM;
  const float* kp = k + (size_t)bh * S_LEN * D_DIM;
  const float* vp = v + (size_t)bh * S_LEN * D_DIM;
  const int*   mp = mask + (size_t)b * S_LEN * S_LEN;
  float* outO = out + (size_t)bh * S_LEN * D_DIM;
  float* outA = out + (size_t)ATTN_OFF + (size_t)bh * S_LEN * S_LEN;

  const int qbase = qt * QT;
  const int qrowC = qbase + wave * 16 + quad * 4;

  const float QSCALE = 0.18033688011112042f;
  short8v qa[2];
  {
    const int qrow = qbase + wave * 16 + l16;
    const float* src = qp + (size_t)qrow * D_DIM + quad * 8;
#pragma unroll
    for (int c = 0; c < 2; ++c) {
      float4v x0 = *(const float4v*)(src + c * 32);
      float4v x1 = *(const float4v*)(src + c * 32 + 4);
      short8v t;
      t[0] = f2bf(x0[0] * QSCALE); t[1] = f2bf(x0[1] * QSCALE);
      t[2] = f2bf(x0[2] * QSCALE); t[3] = f2bf(x0[3] * QSCALE);
      t[4] = f2bf(x1[0] * QSCALE); t[5] = f2bf(x1[1] * QSCALE);
      t[6] = f2bf(x1[2] * QSCALE); t[7] = f2bf(x1[3] * QSCALE);
      qa[c] = t;
    }
  }

  float lsum[4] = {0.f, 0.f, 0.f, 0.f};

#pragma unroll 1
  for (int kt = 0; kt < NIT; ++kt) {
#pragma unroll
    for (int i = 0; i < 4; ++i) {
      int f = tid + i * 256;
      int row = f >> 4;
      int col = (f & 15) * 4;
      float4v x = *(const float4v*)(kp + (size_t)(kt * KTILE + row) * D_DIM + col);
      short4v y;
      y[0] = f2bf(x[0]); y[1] = f2bf(x[1]); y[2] = f2bf(x[2]); y[3] = f2bf(x[3]);
      *(short4v*)(lds_k + row * LDK + col) = y;
    }
    __syncthreads();

    unsigned long long mrow[4];
    if (PACKED) {
#pragma unroll
      for (int r = 0; r < 4; ++r)
        mrow[r] = pm[((size_t)b * S_LEN + qrowC + r) * NW + kt];
    }
#pragma unroll
    for (int t = 0; t < 4; ++t) {
      float4v acc = {0.f, 0.f, 0.f, 0.f};
#pragma unroll
      for (int c = 0; c < 2; ++c) {
        short8v bf = *(const short8v*)(lds_k + (t * 16 + l16) * LDK + c * 32 + quad * 8);
        acc = __builtin_amdgcn_mfma_f32_16x16x32_bf16(qa[c], bf, acc, 0, 0, 0);
      }
      const int kcol = kt * KTILE + t * 16 + l16;
#pragma unroll
      for (int r = 0; r < 4; ++r) {
        bool mv = PACKED ? (((mrow[r] >> (t * 16 + l16)) & 1ull) != 0)
                         : (mp[(size_t)(qrowC + r) * S_LEN + kcol] != 0);
        float p = mv ? exp2f(acc[r]) : 0.f;
        lsum[r] += p;
      }
    }
    __syncthreads();
  }

  float invl[4];
#pragma unroll
  for (int r = 0; r < 4; ++r) {
    float s = lsum[r];
    s += __shfl_xor(s, 1);
    s += __shfl_xor(s, 2);
    s += __shfl_xor(s, 4);
    s += __shfl_xor(s, 8);
    invl[r] = 1.0f / s;
  }

  float4v oacc[4];
#pragma unroll
  for (int dt = 0; dt < 4; ++dt) oacc[dt] = (float4v){0.f, 0.f, 0.f, 0.f};

#pragma unroll 1
  for (int kt = 0; kt < NIT; ++kt) {
#pragma unroll
    for (int i = 0; i < 4; ++i) {
      int f = tid + i * 256;
      int row = f >> 4;
      int col = (f & 15) * 4;
      float4v x = *(const float4v*)(kp + (size_t)(kt * KTILE + row) * D_DIM + col);
      short4v y;
      y[0] = f2bf(x[0]); y[1] = f2bf(x[1]); y[2] = f2bf(x[2]); y[3] = f2bf(x[3]);
      *(short4v*)(lds_k + row * LDK + col) = y;
    }
    {
      const int d = tid & 63;
      const int krg = (tid >> 6) * 4;
#pragma unroll
      for (int i = 0; i < 4; ++i) {
        int kr0 = i * 16 + krg;
        short4v y;
#pragma unroll
        for (int j = 0; j < 4; ++j) {
          float x = vp[(size_t)(kt * KTILE + kr0 + j) * D_DIM + d];
          y[j] = f2bf(x);
        }
        *(short4v*)(lds_vt + d * LDK + kr0) = y;
      }
    }
    __syncthreads();

    unsigned long long mrow[4];
    if (PACKED) {
#pragma unroll
      for (int r = 0; r < 4; ++r)
        mrow[r] = pm[((size_t)b * S_LEN + qrowC + r) * NW + kt];
    }
#pragma unroll
    for (int t = 0; t < 4; ++t) {
      float4v acc = {0.f, 0.f, 0.f, 0.f};
#pragma unroll
      for (int c = 0; c < 2; ++c) {
        short8v bf = *(const short8v*)(lds_k + (t * 16 + l16) * LDK + c * 32 + quad * 8);
        acc = __builtin_amdgcn_mfma_f32_16x16x32_bf16(qa[c], bf, acc, 0, 0, 0);
      }
      const int kcol = kt * KTILE + t * 16 + l16;
      short* prow = lds_p + (wave * 16 + quad * 4) * LDK + t * 16 + l16;
#pragma unroll
      for (int r = 0; r < 4; ++r) {
        bool mv = PACKED ? (((mrow[r] >> (t * 16 + l16)) & 1ull) != 0)
                         : (mp[(size_t)(qrowC + r) * S_LEN + kcol] != 0);
        float p = mv ? exp2f(acc[r]) * invl[r] : 0.f;
        prow[r * LDK] = f2bf(p);
      }
    }

    {
      const int row16 = lane >> 2;
      const int cg = (lane & 3) * 16;
      const short* src = lds_p + (wave * 16 + row16) * LDK + cg;
      short8v p0 = *(const short8v*)src;
      short8v p1 = *(const short8v*)(src + 8);
      float* arow = outA + (size_t)(qbase + wave * 16 + row16) * S_LEN + kt * KTILE + cg;
      float4v f0 = {bf2f(p0[0]), bf2f(p0[1]), bf2f(p0[2]), bf2f(p0[3])};
      float4v f1 = {bf2f(p0[4]), bf2f(p0[5]), bf2f(p0[6]), bf2f(p0[7])};
      float4v f2 = {bf2f(p1[0]), bf2f(p1[1]), bf2f(p1[2]), bf2f(p1[3])};
      float4v f3 = {bf2f(p1[4]), bf2f(p1[5]), bf2f(p1[6]), bf2f(p1[7])};
      *(float4v*)(arow)      = f0;
      *(float4v*)(arow + 4)  = f1;
      *(float4v*)(arow + 8)  = f2;
      *(float4v*)(arow + 12) = f3;
    }

#pragma unroll
    for (int c = 0; c < 2; ++c) {
      short8v pa = *(const short8v*)(lds_p + (wave * 16 + l16) * LDK + c * 32 + quad * 8);
#pragma unroll
      for (int dt = 0; dt < 4; ++dt) {
        short8v vb = *(const short8v*)(lds_vt + (dt * 16 + l16) * LDK + c * 32 + quad * 8);
        oacc[dt] = __builtin_amdgcn_mfma_f32_16x16x32_bf16(pa, vb, oacc[dt], 0, 0, 0);
      }
    }
    __syncthreads();
  }

  {
    float* orow = outO + (size_t)qrowC * D_DIM + l16;
#pragma unroll
    for (int dt = 0; dt < 4; ++dt) {
#pragma unroll
      for (int r = 0; r < 4; ++r) {
        orow[(size_t)r * D_DIM + dt * 16] = oacc[dt][r];
      }
    }
  }
}

extern "C" void kernel_launch(void* const* d_in, const int* in_sizes, int n_in,
                              void* d_out, int out_size, void* d_ws, size_t ws_size,
                              hipStream_t stream) {
  const float* q = (const float*)d_in[0];
  const float* k = (const float*)d_in[1];
  const float* v = (const float*)d_in[2];
  const int* mask = (const int*)d_in[3];
  float* out = (float*)d_out;

  const int BH = 2 * 16;
  dim3 grid(BH * (S_LEN / QT));  // 1024 blocks
  dim3 block(256);

  const int nwords = 2 * S_LEN * NW;                 // 131072
  const size_t pm_bytes = (size_t)nwords * 8;        // 1 MiB
  const size_t kbs_bytes = (size_t)BH * S_LEN * D_DIM * 2;  // 8 MiB
  const size_t kbs_off = pm_bytes;
  const size_t vts_off = kbs_off + kbs_bytes;
  const size_t need = vts_off + kbs_bytes;           // 17 MiB

  if (ws_size >= need) {
    unsigned long long* pm = (unsigned long long*)d_ws;
    short* kbs = (short*)((char*)d_ws + kbs_off);
    short* vts = (short*)((char*)d_ws + vts_off);
    prep_kernel<<<3328, 256, 0, stream>>>(k, v, mask, kbs, vts, pm, nwords);
    sdpa_fused<<<grid, block, 0, stream>>>(q, kbs, vts, pm, out);
  } else if (ws_size >= pm_bytes) {
    unsigned long long* pm = (unsigned long long*)d_ws;
    pack_mask_kernel<<<256, 256, 0, stream>>>(mask, pm, nwords);
    sdpa_kernel<true><<<grid, block, 0, stream>>>(q, k, v, mask, pm, out);
  } else {
    sdpa_kernel<false><<<grid, block, 0, stream>>>(q, k, v, mask, nullptr, out);
  }
}

// Round 4
// 837.502 us; speedup vs baseline: 1.3187x; 1.3187x over previous
//
#include <hip/hip_runtime.h>
#include <hip/hip_bf16.h>

// ScaledDotProductAttention: B=2,H=16,S=2048,D=64, T=8, outputs (O, attn) fp32.
// R5: R4 minus ALL nontemporal stores. R4's counters showed NT stores caused 63%
// HBM write amplification (880 MB vs 528 MiB mandatory) and capped the kernel at
// ~1.5 TB/s write throughput: the attn writeback is 64 scattered 16B pieces per
// instruction, which only L2 write-combining (normal stores) can merge into full
// lines. Kept: deferred attn writeback (drains under next tile's compute), fused
// prep kernel, global_load_lds double-buffered staging, XCD-aware block swizzle.

using short4v = __attribute__((ext_vector_type(4))) short;
using short8v = __attribute__((ext_vector_type(8))) short;
using float4v = __attribute__((ext_vector_type(4))) float;

#define S_LEN 2048
#define D_DIM 64
#define QT 64                 // q rows per block
#define KTILE 64              // k cols per iteration
#define NIT (S_LEN / KTILE)   // 32
#define NW (S_LEN / 64)       // 32 packed 64-bit words per mask row
#define LDK 72                // padded LDS row stride (shorts) for lds_p / fallback
#define ATTN_OFF (2 * 16 * 2048 * 64)
#define TILE_SH (KTILE * D_DIM)  // 4096 shorts = 8 KiB per tile

typedef __attribute__((address_space(1))) const unsigned int gu32;
typedef __attribute__((address_space(3))) unsigned int lu32;

__device__ __forceinline__ short f2bf(float x) {
  __hip_bfloat16 h = __float2bfloat16(x);
  return __builtin_bit_cast(short, h);
}
__device__ __forceinline__ float bf2f(short s) {
  return __builtin_bit_cast(float, ((unsigned)(unsigned short)s) << 16);
}

// ---------------- fused prep: K swizzle + V^T tile swizzle + mask pack ----------------
// blocks [0,2048): K fp32 -> bf16 XOR-swizzled rows.
//   stored[kr][slot] (16B granules) = K[kr][(slot^(kr&7))*8 ..+8]
// blocks [2048,3072): V fp32 -> bf16 transposed tiles, swizzled.
//   vts tile (bh,kt): stored[d][slot] = V[kt*64 + (slot^(d&7))*8 ..+8][d]
// blocks [3072,3328): mask int32 -> 64-col bitmask words.
__global__ __launch_bounds__(256) void prep_kernel(
    const float* __restrict__ k, const float* __restrict__ v,
    const int* __restrict__ mask, short* __restrict__ kbs,
    short* __restrict__ vts, unsigned long long* __restrict__ pm, int nwords) {
  __shared__ short lds_t[64 * 72];
  const int tid = threadIdx.x;
  const int bid = blockIdx.x;
  if (bid < 2048) {
    int g = bid * 256 + tid;  // granule id, 0..524287
    int kr = g >> 3;          // global row (bh*2048 + s)
    int slot = g & 7;
    const float* src = k + (size_t)kr * D_DIM + ((slot ^ (kr & 7)) << 3);
    float4v a = *(const float4v*)src;
    float4v b = *(const float4v*)(src + 4);
    short8v t;
    t[0] = f2bf(a[0]); t[1] = f2bf(a[1]); t[2] = f2bf(a[2]); t[3] = f2bf(a[3]);
    t[4] = f2bf(b[0]); t[5] = f2bf(b[1]); t[6] = f2bf(b[2]); t[7] = f2bf(b[3]);
    *(short8v*)(kbs + (size_t)g * 8) = t;
  } else if (bid < 3072) {
    const int vb = bid - 2048;
    const int bh = vb >> 5;
    const int kt = vb & 31;
    const float* vp = v + ((size_t)bh * S_LEN + kt * KTILE) * D_DIM;
#pragma unroll
    for (int i = 0; i < 4; ++i) {
      int idx = tid + i * 256;  // 0..1023, 4 floats each
      int s = idx >> 4;         // seq within tile
      int d0 = (idx & 15) * 4;
      float4v x = *(const float4v*)(vp + (size_t)s * D_DIM + d0);
#pragma unroll
      for (int j = 0; j < 4; ++j) lds_t[(d0 + j) * 72 + s] = f2bf(x[j]);
    }
    __syncthreads();
    short* dst = vts + (size_t)vb * TILE_SH;
#pragma unroll
    for (int i = 0; i < 2; ++i) {
      int g = tid + i * 256;  // 0..511 granules
      int d = g >> 3;
      int slot = g & 7;
      int lsrc = slot ^ (d & 7);
      short8v t = *(const short8v*)(lds_t + d * 72 + lsrc * 8);
      *(short8v*)(dst + g * 8) = t;
    }
  } else {
    const int lane = tid & 63;
    int gw = ((bid - 3072) * 256 + tid) >> 6;
    const int stride = (256 * 256) >> 6;  // 1024
    for (int w = gw; w < nwords; w += stride) {
      int m = mask[(size_t)w * 64 + lane];
      unsigned long long bits = __ballot(m != 0);
      if (lane == 0) pm[w] = bits;
    }
  }
}

// standalone mask pack (middle fallback path)
__global__ __launch_bounds__(256) void pack_mask_kernel(
    const int* __restrict__ mask, unsigned long long* __restrict__ pm, int nwords) {
  const int lane = threadIdx.x & 63;
  int gw = (blockIdx.x * blockDim.x + threadIdx.x) >> 6;
  const int stride = (gridDim.x * blockDim.x) >> 6;
  for (int w = gw; w < nwords; w += stride) {
    int m = mask[(size_t)w * 64 + lane];
    unsigned long long bits = __ballot(m != 0);
    if (lane == 0) pm[w] = bits;
  }
}

// ---------------- async stage: one wave moves 2 KiB of an 8 KiB tile ----------------
__device__ __forceinline__ void stage_wave(const short* __restrict__ g, short* l,
                                           int wave, int lane) {
  const short* s0 = g + wave * 1024 + lane * 8;  // per-lane 16B source
  short* d0 = l + wave * 1024;                   // wave-uniform LDS base
  __builtin_amdgcn_global_load_lds((gu32*)s0, (lu32*)d0, 16, 0, 0);
  __builtin_amdgcn_global_load_lds((gu32*)(s0 + 512), (lu32*)(d0 + 512), 16, 0, 0);
}

// ---------------- main fused kernel ----------------
__global__ __launch_bounds__(256, 3) void sdpa_fused(
    const float* __restrict__ q, const short* __restrict__ kbs,
    const short* __restrict__ vts, const unsigned long long* __restrict__ pm,
    float* __restrict__ out) {
  __shared__ __align__(16) short lds_k[2][TILE_SH];   // K tiles, swizzled bf16
  __shared__ __align__(16) short lds_vt[2][TILE_SH];  // V^T tiles, swizzled bf16
  __shared__ short lds_p[QT * LDK];                   // P tile bf16 (per-wave rows)

  const int tid  = threadIdx.x;
  const int wave = tid >> 6;
  const int lane = tid & 63;
  const int quad = lane >> 4;
  const int l16  = lane & 15;

  // XCD-aware swizzle: 1024 wgs, 8 XCDs -> contiguous 128-block chunk per XCD
  const int blk = (blockIdx.x & 7) * 128 + (blockIdx.x >> 3);
  const int qt  = blk & (NIT - 1);
  const int bh  = blk >> 5;
  const int b   = bh >> 4;

  const float* qp = q + (size_t)bh * S_LEN * D_DIM;
  const short* kb_g = kbs + (size_t)bh * S_LEN * D_DIM;
  const short* vt_g = vts + (size_t)bh * (NIT * TILE_SH);
  float* outO = out + (size_t)bh * S_LEN * D_DIM;
  float* outA = out + (size_t)ATTN_OFF + (size_t)bh * S_LEN * S_LEN;

  const int qbase = qt * QT;
  const int qrowC = qbase + wave * 16 + quad * 4;  // C/D: row = quad*4 + reg

  // ---- Q fragments; scale log2(e)/8 folded in ----
  const float QSCALE = 0.18033688011112042f;
  short8v qa[2];
  {
    const int qrow = qbase + wave * 16 + l16;  // A-operand: m = lane&15
    const float* src = qp + (size_t)qrow * D_DIM + quad * 8;
#pragma unroll
    for (int c = 0; c < 2; ++c) {
      float4v x0 = *(const float4v*)(src + c * 32);
      float4v x1 = *(const float4v*)(src + c * 32 + 4);
      short8v t;
      t[0] = f2bf(x0[0] * QSCALE); t[1] = f2bf(x0[1] * QSCALE);
      t[2] = f2bf(x0[2] * QSCALE); t[3] = f2bf(x0[3] * QSCALE);
      t[4] = f2bf(x1[0] * QSCALE); t[5] = f2bf(x1[1] * QSCALE);
      t[6] = f2bf(x1[2] * QSCALE); t[7] = f2bf(x1[3] * QSCALE);
      qa[c] = t;
    }
  }

  const unsigned long long* pmrow = pm + ((size_t)b * S_LEN + qrowC) * NW;

  // ================= pass 1: row sums of exp =================
  float lsum[4] = {0.f, 0.f, 0.f, 0.f};
  unsigned long long mrow_c[4];
  unsigned long long mrow_n[4] = {0ull, 0ull, 0ull, 0ull};
#pragma unroll
  for (int r = 0; r < 4; ++r) mrow_c[r] = pmrow[(size_t)r * NW];
  stage_wave(kb_g, lds_k[0], wave, lane);
  __syncthreads();

#pragma unroll 1
  for (int kt = 0; kt < NIT; ++kt) {
    if (kt + 1 < NIT) {
#pragma unroll
      for (int r = 0; r < 4; ++r) mrow_n[r] = pmrow[(size_t)r * NW + kt + 1];
      stage_wave(kb_g + (kt + 1) * TILE_SH, lds_k[(kt + 1) & 1], wave, lane);
    }
    const short* kbuf = lds_k[kt & 1];
#pragma unroll
    for (int t = 0; t < 4; ++t) {
      float4v acc = {0.f, 0.f, 0.f, 0.f};
      const int row = t * 16 + l16;
      const int sw = (row & 7) << 3;  // XOR swizzle, short units (16B granules)
#pragma unroll
      for (int c = 0; c < 2; ++c) {
        short8v bf = *(const short8v*)(kbuf + row * 64 + (((c * 32) + quad * 8) ^ sw));
        acc = __builtin_amdgcn_mfma_f32_16x16x32_bf16(qa[c], bf, acc, 0, 0, 0);
      }
#pragma unroll
      for (int r = 0; r < 4; ++r) {
        bool mv = ((mrow_c[r] >> (t * 16 + l16)) & 1ull) != 0;
        float p = mv ? exp2f(acc[r]) : 0.f;
        lsum[r] += p;
      }
    }
#pragma unroll
    for (int r = 0; r < 4; ++r) mrow_c[r] = mrow_n[r];
    __syncthreads();  // implicit vmcnt(0): tile kt+1 landed; buffers safe
  }

  float invl[4];
#pragma unroll
  for (int r = 0; r < 4; ++r) {
    float s = lsum[r];
    s += __shfl_xor(s, 1);
    s += __shfl_xor(s, 2);
    s += __shfl_xor(s, 4);
    s += __shfl_xor(s, 8);
    invl[r] = 1.0f / s;
  }

  // ================= pass 2: attn write + PV =================
  float4v oacc[4];
#pragma unroll
  for (int dt = 0; dt < 4; ++dt) oacc[dt] = (float4v){0.f, 0.f, 0.f, 0.f};

#pragma unroll
  for (int r = 0; r < 4; ++r) mrow_c[r] = pmrow[(size_t)r * NW];
  stage_wave(kb_g, lds_k[0], wave, lane);
  stage_wave(vt_g, lds_vt[0], wave, lane);
  __syncthreads();

  // deferred attn writeback state (tile kt-1's P, read back into regs in iter kt-1)
  const int row16 = lane >> 2;
  const int cg = (lane & 3) * 16;
  float* arow_base = outA + (size_t)(qbase + wave * 16 + row16) * S_LEN + cg;
  short8v pp0, pp1;

#pragma unroll 1
  for (int kt = 0; kt < NIT; ++kt) {
    // (1) deferred attn store of tile kt-1: issued at top so it drains during
    // this iteration's compute instead of stalling the pre-barrier vmcnt(0).
    if (kt > 0) {
      float* arow = arow_base + (kt - 1) * KTILE;
      float4v f0 = {bf2f(pp0[0]), bf2f(pp0[1]), bf2f(pp0[2]), bf2f(pp0[3])};
      float4v f1 = {bf2f(pp0[4]), bf2f(pp0[5]), bf2f(pp0[6]), bf2f(pp0[7])};
      float4v f2 = {bf2f(pp1[0]), bf2f(pp1[1]), bf2f(pp1[2]), bf2f(pp1[3])};
      float4v f3 = {bf2f(pp1[4]), bf2f(pp1[5]), bf2f(pp1[6]), bf2f(pp1[7])};
      *(float4v*)(arow)      = f0;
      *(float4v*)(arow + 4)  = f1;
      *(float4v*)(arow + 8)  = f2;
      *(float4v*)(arow + 12) = f3;
    }
    // (2) next-tile mask + K/V prefetch
    if (kt + 1 < NIT) {
#pragma unroll
      for (int r = 0; r < 4; ++r) mrow_n[r] = pmrow[(size_t)r * NW + kt + 1];
      stage_wave(kb_g + (kt + 1) * TILE_SH, lds_k[(kt + 1) & 1], wave, lane);
      stage_wave(vt_g + (kt + 1) * TILE_SH, lds_vt[(kt + 1) & 1], wave, lane);
    }
    const short* kbuf = lds_k[kt & 1];
    const short* vbuf = lds_vt[kt & 1];

    // (3) QK^T + P staging
#pragma unroll
    for (int t = 0; t < 4; ++t) {
      float4v acc = {0.f, 0.f, 0.f, 0.f};
      const int row = t * 16 + l16;
      const int sw = (row & 7) << 3;
#pragma unroll
      for (int c = 0; c < 2; ++c) {
        short8v bf = *(const short8v*)(kbuf + row * 64 + (((c * 32) + quad * 8) ^ sw));
        acc = __builtin_amdgcn_mfma_f32_16x16x32_bf16(qa[c], bf, acc, 0, 0, 0);
      }
      short* prow = lds_p + (wave * 16 + quad * 4) * LDK + t * 16 + l16;
#pragma unroll
      for (int r = 0; r < 4; ++r) {
        bool mv = ((mrow_c[r] >> (t * 16 + l16)) & 1ull) != 0;
        float p = mv ? exp2f(acc[r]) * invl[r] : 0.f;
        prow[r * LDK] = f2bf(p);  // stage P (C/D -> A layout via LDS)
      }
    }

    // (4) same-wave P readback into carry registers (DS in-order per wave)
    {
      const short* src = lds_p + (wave * 16 + row16) * LDK + cg;
      pp0 = *(const short8v*)src;
      pp1 = *(const short8v*)(src + 8);
    }

    // (5) PV
#pragma unroll
    for (int c = 0; c < 2; ++c) {
      short8v pa = *(const short8v*)(lds_p + (wave * 16 + l16) * LDK + c * 32 + quad * 8);
#pragma unroll
      for (int dt = 0; dt < 4; ++dt) {
        const int row = dt * 16 + l16;
        const int sw = (row & 7) << 3;
        short8v vb = *(const short8v*)(vbuf + row * 64 + (((c * 32) + quad * 8) ^ sw));
        oacc[dt] = __builtin_amdgcn_mfma_f32_16x16x32_bf16(pa, vb, oacc[dt], 0, 0, 0);
      }
    }
#pragma unroll
    for (int r = 0; r < 4; ++r) mrow_c[r] = mrow_n[r];
    __syncthreads();
  }

  // final tile's deferred attn store
  {
    float* arow = arow_base + (NIT - 1) * KTILE;
    float4v f0 = {bf2f(pp0[0]), bf2f(pp0[1]), bf2f(pp0[2]), bf2f(pp0[3])};
    float4v f1 = {bf2f(pp0[4]), bf2f(pp0[5]), bf2f(pp0[6]), bf2f(pp0[7])};
    float4v f2 = {bf2f(pp1[0]), bf2f(pp1[1]), bf2f(pp1[2]), bf2f(pp1[3])};
    float4v f3 = {bf2f(pp1[4]), bf2f(pp1[5]), bf2f(pp1[6]), bf2f(pp1[7])};
    *(float4v*)(arow)      = f0;
    *(float4v*)(arow + 4)  = f1;
    *(float4v*)(arow + 8)  = f2;
    *(float4v*)(arow + 12) = f3;
  }

  {
    float* orow = outO + (size_t)qrowC * D_DIM + l16;
#pragma unroll
    for (int dt = 0; dt < 4; ++dt) {
#pragma unroll
      for (int r = 0; r < 4; ++r) {
        orow[(size_t)r * D_DIM + dt * 16] = oacc[dt][r];
      }
    }
  }
}

// ================= fallback (R2 kernel, small workspace) =================
template <bool PACKED>
__global__ __launch_bounds__(256, 4) void sdpa_kernel(
    const float* __restrict__ q, const float* __restrict__ k,
    const float* __restrict__ v, const int* __restrict__ mask,
    const unsigned long long* __restrict__ pm, float* __restrict__ out) {
  __shared__ short lds_k[KTILE * LDK];
  __shared__ short lds_vt[D_DIM * LDK];
  __shared__ short lds_p[QT * LDK];

  const int tid  = threadIdx.x;
  const int wave = tid >> 6;
  const int lane = tid & 63;
  const int quad = lane >> 4;
  const int l16  = lane & 15;

  const int blk = blockIdx.x;
  const int qt  = blk & (NIT - 1);
  const int bh  = blk >> 5;
  const int b   = bh >> 4;

  const float* qp = q + (size_t)bh * S_LEN * D_DIM;
  const float* kp = k + (size_t)bh * S_LEN * D_DIM;
  const float* vp = v + (size_t)bh * S_LEN * D_DIM;
  const int*   mp = mask + (size_t)b * S_LEN * S_LEN;
  float* outO = out + (size_t)bh * S_LEN * D_DIM;
  float* outA = out + (size_t)ATTN_OFF + (size_t)bh * S_LEN * S_LEN;

  const int qbase = qt * QT;
  const int qrowC = qbase + wave * 16 + quad * 4;

  const float QSCALE = 0.18033688011112042f;
  short8v qa[2];
  {
    const int qrow = qbase + wave * 16 + l16;
    const float* src = qp + (size_t)qrow * D_DIM + quad * 8;
#pragma unroll
    for (int c = 0; c < 2; ++c) {
      float4v x0 = *(const float4v*)(src + c * 32);
      float4v x1 = *(const float4v*)(src + c * 32 + 4);
      short8v t;
      t[0] = f2bf(x0[0] * QSCALE); t[1] = f2bf(x0[1] * QSCALE);
      t[2] = f2bf(x0[2] * QSCALE); t[3] = f2bf(x0[3] * QSCALE);
      t[4] = f2bf(x1[0] * QSCALE); t[5] = f2bf(x1[1] * QSCALE);
      t[6] = f2bf(x1[2] * QSCALE); t[7] = f2bf(x1[3] * QSCALE);
      qa[c] = t;
    }
  }

  float lsum[4] = {0.f, 0.f, 0.f, 0.f};

#pragma unroll 1
  for (int kt = 0; kt < NIT; ++kt) {
#pragma unroll
    for (int i = 0; i < 4; ++i) {
      int f = tid + i * 256;
      int row = f >> 4;
      int col = (f & 15) * 4;
      float4v x = *(const float4v*)(kp + (size_t)(kt * KTILE + row) * D_DIM + col);
      short4v y;
      y[0] = f2bf(x[0]); y[1] = f2bf(x[1]); y[2] = f2bf(x[2]); y[3] = f2bf(x[3]);
      *(short4v*)(lds_k + row * LDK + col) = y;
    }
    __syncthreads();

    unsigned long long mrow[4];
    if (PACKED) {
#pragma unroll
      for (int r = 0; r < 4; ++r)
        mrow[r] = pm[((size_t)b * S_LEN + qrowC + r) * NW + kt];
    }
#pragma unroll
    for (int t = 0; t < 4; ++t) {
      float4v acc = {0.f, 0.f, 0.f, 0.f};
#pragma unroll
      for (int c = 0; c < 2; ++c) {
        short8v bf = *(const short8v*)(lds_k + (t * 16 + l16) * LDK + c * 32 + quad * 8);
        acc = __builtin_amdgcn_mfma_f32_16x16x32_bf16(qa[c], bf, acc, 0, 0, 0);
      }
      const int kcol = kt * KTILE + t * 16 + l16;
#pragma unroll
      for (int r = 0; r < 4; ++r) {
        bool mv = PACKED ? (((mrow[r] >> (t * 16 + l16)) & 1ull) != 0)
                         : (mp[(size_t)(qrowC + r) * S_LEN + kcol] != 0);
        float p = mv ? exp2f(acc[r]) : 0.f;
        lsum[r] += p;
      }
    }
    __syncthreads();
  }

  float invl[4];
#pragma unroll
  for (int r = 0; r < 4; ++r) {
    float s = lsum[r];
    s += __shfl_xor(s, 1);
    s += __shfl_xor(s, 2);
    s += __shfl_xor(s, 4);
    s += __shfl_xor(s, 8);
    invl[r] = 1.0f / s;
  }

  float4v oacc[4];
#pragma unroll
  for (int dt = 0; dt < 4; ++dt) oacc[dt] = (float4v){0.f, 0.f, 0.f, 0.f};

#pragma unroll 1
  for (int kt = 0; kt < NIT; ++kt) {
#pragma unroll
    for (int i = 0; i < 4; ++i) {
      int f = tid + i * 256;
      int row = f >> 4;
      int col = (f & 15) * 4;
      float4v x = *(const float4v*)(kp + (size_t)(kt * KTILE + row) * D_DIM + col);
      short4v y;
      y[0] = f2bf(x[0]); y[1] = f2bf(x[1]); y[2] = f2bf(x[2]); y[3] = f2bf(x[3]);
      *(short4v*)(lds_k + row * LDK + col) = y;
    }
    {
      const int d = tid & 63;
      const int krg = (tid >> 6) * 4;
#pragma unroll
      for (int i = 0; i < 4; ++i) {
        int kr0 = i * 16 + krg;
        short4v y;
#pragma unroll
        for (int j = 0; j < 4; ++j) {
          float x = vp[(size_t)(kt * KTILE + kr0 + j) * D_DIM + d];
          y[j] = f2bf(x);
        }
        *(short4v*)(lds_vt + d * LDK + kr0) = y;
      }
    }
    __syncthreads();

    unsigned long long mrow[4];
    if (PACKED) {
#pragma unroll
      for (int r = 0; r < 4; ++r)
        mrow[r] = pm[((size_t)b * S_LEN + qrowC + r) * NW + kt];
    }
#pragma unroll
    for (int t = 0; t < 4; ++t) {
      float4v acc = {0.f, 0.f, 0.f, 0.f};
#pragma unroll
      for (int c = 0; c < 2; ++c) {
        short8v bf = *(const short8v*)(lds_k + (t * 16 + l16) * LDK + c * 32 + quad * 8);
        acc = __builtin_amdgcn_mfma_f32_16x16x32_bf16(qa[c], bf, acc, 0, 0, 0);
      }
      const int kcol = kt * KTILE + t * 16 + l16;
      short* prow = lds_p + (wave * 16 + quad * 4) * LDK + t * 16 + l16;
#pragma unroll
      for (int r = 0; r < 4; ++r) {
        bool mv = PACKED ? (((mrow[r] >> (t * 16 + l16)) & 1ull) != 0)
                         : (mp[(size_t)(qrowC + r) * S_LEN + kcol] != 0);
        float p = mv ? exp2f(acc[r]) * invl[r] : 0.f;
        prow[r * LDK] = f2bf(p);
      }
    }

    {
      const int row16 = lane >> 2;
      const int cg = (lane & 3) * 16;
      const short* src = lds_p + (wave * 16 + row16) * LDK + cg;
      short8v p0 = *(const short8v*)src;
      short8v p1 = *(const short8v*)(src + 8);
      float* arow = outA + (size_t)(qbase + wave * 16 + row16) * S_LEN + kt * KTILE + cg;
      float4v f0 = {bf2f(p0[0]), bf2f(p0[1]), bf2f(p0[2]), bf2f(p0[3])};
      float4v f1 = {bf2f(p0[4]), bf2f(p0[5]), bf2f(p0[6]), bf2f(p0[7])};
      float4v f2 = {bf2f(p1[0]), bf2f(p1[1]), bf2f(p1[2]), bf2f(p1[3])};
      float4v f3 = {bf2f(p1[4]), bf2f(p1[5]), bf2f(p1[6]), bf2f(p1[7])};
      *(float4v*)(arow)      = f0;
      *(float4v*)(arow + 4)  = f1;
      *(float4v*)(arow + 8)  = f2;
      *(float4v*)(arow + 12) = f3;
    }

#pragma unroll
    for (int c = 0; c < 2; ++c) {
      short8v pa = *(const short8v*)(lds_p + (wave * 16 + l16) * LDK + c * 32 + quad * 8);
#pragma unroll
      for (int dt = 0; dt < 4; ++dt) {
        short8v vb = *(const short8v*)(lds_vt + (dt * 16 + l16) * LDK + c * 32 + quad * 8);
        oacc[dt] = __builtin_amdgcn_mfma_f32_16x16x32_bf16(pa, vb, oacc[dt], 0, 0, 0);
      }
    }
    __syncthreads();
  }

  {
    float* orow = outO + (size_t)qrowC * D_DIM + l16;
#pragma unroll
    for (int dt = 0; dt < 4; ++dt) {
#pragma unroll
      for (int r = 0; r < 4; ++r) {
        orow[(size_t)r * D_DIM + dt * 16] = oacc[dt][r];
      }
    }
  }
}

extern "C" void kernel_launch(void* const* d_in, const int* in_sizes, int n_in,
                              void* d_out, int out_size, void* d_ws, size_t ws_size,
                              hipStream_t stream) {
  const float* q = (const float*)d_in[0];
  const float* k = (const float*)d_in[1];
  const float* v = (const float*)d_in[2];
  const int* mask = (const int*)d_in[3];
  float* out = (float*)d_out;

  const int BH = 2 * 16;
  dim3 grid(BH * (S_LEN / QT));  // 1024 blocks
  dim3 block(256);

  const int nwords = 2 * S_LEN * NW;                 // 131072
  const size_t pm_bytes = (size_t)nwords * 8;        // 1 MiB
  const size_t kbs_bytes = (size_t)BH * S_LEN * D_DIM * 2;  // 8 MiB
  const size_t kbs_off = pm_bytes;
  const size_t vts_off = kbs_off + kbs_bytes;
  const size_t need = vts_off + kbs_bytes;           // 17 MiB

  if (ws_size >= need) {
    unsigned long long* pm = (unsigned long long*)d_ws;
    short* kbs = (short*)((char*)d_ws + kbs_off);
    short* vts = (short*)((char*)d_ws + vts_off);
    prep_kernel<<<3328, 256, 0, stream>>>(k, v, mask, kbs, vts, pm, nwords);
    sdpa_fused<<<grid, block, 0, stream>>>(q, kbs, vts, pm, out);
  } else if (ws_size >= pm_bytes) {
    unsigned long long* pm = (unsigned long long*)d_ws;
    pack_mask_kernel<<<256, 256, 0, stream>>>(mask, pm, nwords);
    sdpa_kernel<true><<<grid, block, 0, stream>>>(q, k, v, mask, pm, out);
  } else {
    sdpa_kernel<false><<<grid, block, 0, stream>>>(q, k, v, mask, nullptr, out);
  }
}